// Round 12
// baseline (171.526 us; speedup 1.0000x reference)
//
#include <hip/hip_runtime.h>
#include <hip/hip_fp8.h>
#include <stdint.h>

#define EPS 1e-8f

constexpr int C  = 256;     // channels (K dim)
constexpr int HW = 16384;   // pixels per image (M and N dims)
constexpr int BM = 128;     // block M tile
constexpr int NG = 1024;    // n-group width per block (16 q-substeps of 64)

typedef __attribute__((ext_vector_type(4))) float floatx4;
typedef long long llong2 __attribute__((ext_vector_type(2)));   // 16B = 2 fp8 k-chunks
typedef unsigned char u8;
typedef unsigned int u32;
typedef unsigned long long u64;

__device__ inline u8 f2fp8(float x) {   // OCP e4m3 (gfx950 HW cvt)
    __hip_fp8_e4m3 h(x);
    return h.__x;
}

// pack 4 floats -> 4 fp8 bytes (little-endian order a,b,c,d)
__device__ inline u32 pk4(float va, float vb, float vc, float vd) {
#if __has_builtin(__builtin_amdgcn_cvt_pk_fp8_f32)
    u32 w = __builtin_amdgcn_cvt_pk_fp8_f32(va, vb, 0, false);   // bytes 0,1
    w = __builtin_amdgcn_cvt_pk_fp8_f32(vc, vd, w, true);        // bytes 2,3
    return w;
#else
    return (u32)f2fp8(va) | ((u32)f2fp8(vb) << 8) |
           ((u32)f2fp8(vc) << 16) | ((u32)f2fp8(vd) << 24);
#endif
}

__device__ inline float fc(const float4& f, int j) {
    return j == 0 ? f.x : j == 1 ? f.y : j == 2 ? f.z : f.w;
}

// ---------------------------------------------------------------------------
// PREP: one pass over a,b -> sumsq_a/b + fp8 fragment arrays.
// 16 pixels x 256 channels per block -> 1024 blocks (4/CU, 4 waves/SIMD —
// R11's 256-block version ran at 1 wave/SIMD, pure latency exposure).
// Thread (pg = tid&3, tc = tid>>2): pixels pg*4..+4 (float4) x channels
// tc*4..+4. Fragment element (p, cc) lives at (g*4+cp)*1024 + lane2*16 +
// half*8 + (cc&7); for a 4-ch group: cb = tc>>1, cp = tc>>4, half=(tc>>3)&1,
// byte offset (tc&1)*4 -> one u32 store per pixel. b normalized, a raw.
__global__ __launch_bounds__(256) void prep_kernel(const float* __restrict__ a,
                                                   const float* __restrict__ b,
                                                   float* __restrict__ sumsq_a,
                                                   float* __restrict__ sumsq_b,
                                                   u8* __restrict__ aF, u8* __restrict__ bF) {
    __shared__ float red[16][65];    // [pixel][tc] (65: bank-spread)
    __shared__ float invb_sh[16];
    const int tid = threadIdx.x;
    const int pg = tid & 3, tc = tid >> 2;
    const int p0 = blockIdx.x * 16, pb = pg * 4;
    const int g = p0 >> 4;
    const int cb = tc >> 1, cp = tc >> 4, half = (tc >> 3) & 1, qd = tc & 1;

    // ---- b: 4 channels x 4 pixels + per-pixel partial sumsq
    float4 bv[4];
    float ss0 = 0.f, ss1 = 0.f, ss2 = 0.f, ss3 = 0.f;
    #pragma unroll
    for (int i = 0; i < 4; ++i) {
        bv[i] = *(const float4*)&b[(size_t)(tc * 4 + i) * HW + p0 + pb];
        ss0 += bv[i].x * bv[i].x; ss1 += bv[i].y * bv[i].y;
        ss2 += bv[i].z * bv[i].z; ss3 += bv[i].w * bv[i].w;
    }
    red[pb + 0][tc] = ss0; red[pb + 1][tc] = ss1;
    red[pb + 2][tc] = ss2; red[pb + 3][tc] = ss3;
    __syncthreads();
    if (tid < 16) {
        float B = 0.f;
        #pragma unroll
        for (int k = 0; k < 64; ++k) B += red[tid][k];
        sumsq_b[p0 + tid] = B;
        invb_sh[tid] = 1.0f / (sqrtf(B + EPS) + EPS);
    }
    __syncthreads();

    #pragma unroll
    for (int j = 0; j < 4; ++j) {
        int p = p0 + pb + j;
        float inv = invb_sh[pb + j];
        u32 w = pk4(fc(bv[0], j) * inv, fc(bv[1], j) * inv,
                    fc(bv[2], j) * inv, fc(bv[3], j) * inv);
        int lane2 = (p & 15) + ((cb & 3) << 4);
        *(u32*)(bF + (((size_t)(g * 4 + cp)) << 10) + lane2 * 16 + half * 8 + qd * 4) = w;
    }

    // ---- a: raw fragments + sumsq partials
    float4 av[4];
    ss0 = ss1 = ss2 = ss3 = 0.f;
    #pragma unroll
    for (int i = 0; i < 4; ++i) {
        av[i] = *(const float4*)&a[(size_t)(tc * 4 + i) * HW + p0 + pb];
        ss0 += av[i].x * av[i].x; ss1 += av[i].y * av[i].y;
        ss2 += av[i].z * av[i].z; ss3 += av[i].w * av[i].w;
    }
    #pragma unroll
    for (int j = 0; j < 4; ++j) {
        int p = p0 + pb + j;
        u32 w = pk4(fc(av[0], j), fc(av[1], j), fc(av[2], j), fc(av[3], j));
        int lane2 = (p & 15) + ((cb & 3) << 4);
        *(u32*)(aF + (((size_t)(g * 4 + cp)) << 10) + lane2 * 16 + half * 8 + qd * 4) = w;
    }
    __syncthreads();   // red reuse
    red[pb + 0][tc] = ss0; red[pb + 1][tc] = ss1;
    red[pb + 2][tc] = ss2; red[pb + 3][tc] = ss3;
    __syncthreads();
    if (tid < 16) {
        float A = 0.f;
        #pragma unroll
        for (int k = 0; k < 64; ++k) A += red[tid][k];
        sumsq_a[p0 + tid] = A;
    }
}

// ---------------------------------------------------------------------------
// G: fused GEMM + argmax. Register-resident A; N-loop over 16 q-substeps of
// 64 cols (NG=1024). Wave tile 64x32 (2m x 2n), 3 waves/SIMD (R10: occupancy
// is the lever). NEW: biased-key argmax — acc initialized to +64.0 so scores
// are positive floats (u32-monotone, no sign fixup); 5-bit candidate code
// (qt*2+ni, inverted so ties prefer smaller q) packed into low mantissa bits
// via v_and_or_b32 (mask kept in a VGPR), running best = v_max_u32.
// 2 VALU/score vs 3 before; bestv+bestq (32 regs) -> bestk (16 regs).
// Value truncation = 31 ULP @2^6 ≈ 2.4e-4 on s — far below fp8 noise.
__global__ __launch_bounds__(256, 3) void gemm_argmax(const u8* __restrict__ aF,
                                                      const u8* __restrict__ bF,
                                                      u64* __restrict__ packed) {
    const int tid = threadIdx.x;
    const int w = tid >> 6, lane = tid & 63;
    const int q4 = lane >> 4, r15 = lane & 15;
    const int wm = w >> 1, wn = w & 1;

    const u32 bid = blockIdx.x;
    const u32 ng = bid & 15;         // n-group (XCD gets ng and ng+8: 512KB of bF in L2)
    const u32 mt = bid >> 4;         // 0..127 M tile
    const int p0 = (int)mt * BM;

    u32 maskv;                       // 0xFFFFFFE0 in a VGPR so (v&m)|code fuses to v_and_or_b32
    asm("v_mov_b32 %0, 0xFFFFFFE0" : "=v"(maskv));

    // A fragments resident: frag (mi, cp) = 16B covering k-chunks 2cp,2cp+1
    const u8* gA = aF + ((size_t)(mt * 8 + wm * 4) * 4) * 1024 + (u32)lane * 16;
    llong2 Afr[4][4];
    #pragma unroll
    for (int mi = 0; mi < 4; ++mi)
        #pragma unroll
        for (int cp = 0; cp < 4; ++cp)
            Afr[mi][cp] = *(const llong2*)(gA + (u32)(mi * 4 + cp) * 1024);

    // B: col-group (ng*64 + qt*4 + wn*2 + ni), frag cp -> +cp*1024
    const u8* gB = bF + ((size_t)(ng * 64 + wn * 2)) * 4096 + (u32)lane * 16;

    u32 bestk[4][4] = {};            // keys all >= float(64-32) bits > 0
    const u32 qbase = ng * 1024 + wn * 32 + (u32)r15;   // + qt*64 + ni*16

    const floatx4 BIAS = {64.0f, 64.0f, 64.0f, 64.0f};

    llong2 Bfr[2][2];
    #pragma unroll
    for (int ni = 0; ni < 2; ++ni)
        Bfr[0][ni] = *(const llong2*)(gB + (u32)ni * 4096u);

    for (int qt = 0; qt < 16; ++qt) {
        floatx4 acc[4][2];
        #pragma unroll
        for (int mi = 0; mi < 4; ++mi)
            #pragma unroll
            for (int ni = 0; ni < 2; ++ni)
                acc[mi][ni] = BIAS;
        #pragma unroll
        for (int cp = 0; cp < 4; ++cp) {
            const int cur = cp & 1, nxt = cur ^ 1;
            u32 nqt = (cp == 3) ? (u32)(qt + 1 < 16 ? qt + 1 : 15) : (u32)qt;
            u32 ncp = (cp == 3) ? 0u : (u32)(cp + 1);
            #pragma unroll
            for (int ni = 0; ni < 2; ++ni)
                Bfr[nxt][ni] = *(const llong2*)(gB + nqt * 16384u + (u32)ni * 4096u + ncp * 1024u);
            #pragma unroll
            for (int mi = 0; mi < 4; ++mi)
                #pragma unroll
                for (int ni = 0; ni < 2; ++ni)
                    acc[mi][ni] = __builtin_amdgcn_mfma_f32_16x16x32_fp8_fp8(
                        Afr[mi][cp].x, Bfr[cur][ni].x, acc[mi][ni], 0, 0, 0);
            #pragma unroll
            for (int mi = 0; mi < 4; ++mi)
                #pragma unroll
                for (int ni = 0; ni < 2; ++ni)
                    acc[mi][ni] = __builtin_amdgcn_mfma_f32_16x16x32_fp8_fp8(
                        Afr[mi][cp].y, Bfr[cur][ni].y, acc[mi][ni], 0, 0, 0);
        }
        // running argmax: key = (bits & ~31) | code ; best = max_u32
        #pragma unroll
        for (int ni = 0; ni < 2; ++ni) {
            const u32 code = 31u - (u32)(qt * 2 + ni);   // larger code = smaller q
            #pragma unroll
            for (int mi = 0; mi < 4; ++mi)
                #pragma unroll
                for (int reg = 0; reg < 4; ++reg) {
                    u32 key = (__float_as_uint(acc[mi][ni][reg]) & maskv) | code;
                    bestk[mi][reg] = bestk[mi][reg] > key ? bestk[mi][reg] : key;
                }
        }
    }

    // final: decode code -> q, pack u64, shuffle-reduce over r15, 1 atomic/row
    #pragma unroll
    for (int mi = 0; mi < 4; ++mi)
        #pragma unroll
        for (int reg = 0; reg < 4; ++reg) {
            u32 k = bestk[mi][reg];
            u32 code = 31u - (k & 31u);
            u32 q = qbase + (code >> 1) * 64u + (code & 1u) * 16u;
            u64 pk = ((u64)(k & 0xFFFFFFE0u) << 32) | (u64)(0xFFFFFFFFu - q);
            #pragma unroll
            for (int d = 1; d < 16; d <<= 1) {
                u64 o = __shfl_xor((unsigned long long)pk, d);
                pk = o > pk ? o : pk;
            }
            if (r15 == 0)
                atomicMax(&packed[p0 + wm * 64 + mi * 16 + q4 * 4 + reg], pk);
        }
}

// ---------------------------------------------------------------------------
// L: loss from the argmax's own similarity value (no gather).
// High 32 bits of packed = float bits of (s + 64) with low 5 bits zeroed.
__global__ void loss_kernel(const u64* __restrict__ packed,
                            const float* __restrict__ sumsq_a, const float* __restrict__ sumsq_b,
                            float* __restrict__ out) {
    int p = blockIdx.x * 256 + threadIdx.x;
    u64 pk = packed[p];
    float s = __uint_as_float((u32)(pk >> 32)) - 64.0f;
    u32 q = 0xFFFFFFFFu - (u32)(pk & 0xFFFFFFFFull);
    float A = sumsq_a[p], B = sumsq_b[q];
    float dot = s * (sqrtf(B + EPS) + EPS);
    float cossim = dot / ((sqrtf(A) + EPS) * (sqrtf(B) + EPS));
    float v = (1.0f - cossim) * (1.0f / (float)HW);
    #pragma unroll
    for (int d = 1; d < 64; d <<= 1) v += __shfl_xor(v, d);
    if ((threadIdx.x & 63) == 0) atomicAdd(out, v);
}

// ---------------------------------------------------------------------------
extern "C" void kernel_launch(void* const* d_in, const int* in_sizes, int n_in,
                              void* d_out, int out_size, void* d_ws, size_t ws_size,
                              hipStream_t stream) {
    const float* a = (const float*)d_in[0];
    const float* b = (const float*)d_in[1];
    float* out = (float*)d_out;
    char* ws = (char*)d_ws;

    u8*    aF      = (u8*)ws;                                    // 4 MB
    u8*    bF      = (u8*)(ws + (size_t)4 * 1024 * 1024);        // 4 MB
    float* sumsq_a = (float*)(ws + (size_t)8 * 1024 * 1024);     // 64 KB
    float* sumsq_b = sumsq_a + HW;
    u64*   packed  = (u64*)(sumsq_b + HW);                       // 128 KB

    hipMemsetAsync(out, 0, sizeof(float), stream);
    hipMemsetAsync(packed, 0, (size_t)HW * sizeof(u64), stream);

    prep_kernel<<<dim3(HW / 16), 256, 0, stream>>>(a, b, sumsq_a, sumsq_b, aF, bF);
    gemm_argmax<<<dim3((HW / BM) * (HW / NG)), 256, 0, stream>>>(aF, bF, packed);
    loss_kernel<<<dim3(HW / 256), 256, 0, stream>>>(packed, sumsq_a, sumsq_b, out);
}

// Round 13
// 168.373 us; speedup vs baseline: 1.0187x; 1.0187x over previous
//
#include <hip/hip_runtime.h>
#include <hip/hip_fp8.h>
#include <stdint.h>

#define EPS 1e-8f

constexpr int C  = 256;     // channels (K dim)
constexpr int HW = 16384;   // pixels per image (M and N dims)
constexpr int BM = 128;     // block M tile
constexpr int NG = 1024;    // n-group width per block (16 q-substeps of 64)

typedef __attribute__((ext_vector_type(4))) float floatx4;
typedef long long llong2 __attribute__((ext_vector_type(2)));   // 16B = 2 fp8 k-chunks
typedef unsigned char u8;
typedef unsigned int u32;
typedef unsigned long long u64;

__device__ inline u8 f2fp8(float x) {   // OCP e4m3 (gfx950 HW cvt)
    __hip_fp8_e4m3 h(x);
    return h.__x;
}

// pack 4 floats -> 4 fp8 bytes (little-endian order a,b,c,d)
__device__ inline u32 pk4(float va, float vb, float vc, float vd) {
#if __has_builtin(__builtin_amdgcn_cvt_pk_fp8_f32)
    u32 w = __builtin_amdgcn_cvt_pk_fp8_f32(va, vb, 0, false);   // bytes 0,1
    w = __builtin_amdgcn_cvt_pk_fp8_f32(vc, vd, w, true);        // bytes 2,3
    return w;
#else
    return (u32)f2fp8(va) | ((u32)f2fp8(vb) << 8) |
           ((u32)f2fp8(vc) << 16) | ((u32)f2fp8(vd) << 24);
#endif
}

__device__ inline float fc(const float4& f, int j) {
    return j == 0 ? f.x : j == 1 ? f.y : j == 2 ? f.z : f.w;
}

// ---------------------------------------------------------------------------
// PREP: one pass over a,b -> sumsq_a/b + fp8 fragment arrays. Also zeroes
// `packed` (16 u64/block) and `out` (block 0) so the graph needs no memset
// nodes (5 -> 3 dispatches). 16 pixels x 256 channels per block -> 1024
// blocks (4/CU). Thread (pg = tid&3, tc = tid>>2): pixels pg*4..+4 (float4)
// x channels tc*4..+4. Fragment element (p, cc) lives at (g*4+cp)*1024 +
// lane2*16 + half*8 + (cc&7); for a 4-ch group: cb = tc>>1, cp = tc>>4,
// half=(tc>>3)&1, byte (tc&1)*4 -> one u32 store/pixel. b normalized, a raw.
__global__ __launch_bounds__(256) void prep_kernel(const float* __restrict__ a,
                                                   const float* __restrict__ b,
                                                   float* __restrict__ sumsq_a,
                                                   float* __restrict__ sumsq_b,
                                                   u8* __restrict__ aF, u8* __restrict__ bF,
                                                   u64* __restrict__ packed,
                                                   float* __restrict__ out) {
    __shared__ float red[16][65];    // [pixel][tc] (65: bank-spread)
    __shared__ float invb_sh[16];
    const int tid = threadIdx.x;
    const int pg = tid & 3, tc = tid >> 2;
    const int p0 = blockIdx.x * 16, pb = pg * 4;
    const int g = p0 >> 4;
    const int cb = tc >> 1, cp = tc >> 4, half = (tc >> 3) & 1, qd = tc & 1;

    // zero the argmax array (gemm depends on prep, so this is ordered)
    if (tid < 16) packed[blockIdx.x * 16 + tid] = 0;
    if (blockIdx.x == 0 && tid == 0) *out = 0.f;

    // ---- b: 4 channels x 4 pixels + per-pixel partial sumsq
    float4 bv[4];
    float ss0 = 0.f, ss1 = 0.f, ss2 = 0.f, ss3 = 0.f;
    #pragma unroll
    for (int i = 0; i < 4; ++i) {
        bv[i] = *(const float4*)&b[(size_t)(tc * 4 + i) * HW + p0 + pb];
        ss0 += bv[i].x * bv[i].x; ss1 += bv[i].y * bv[i].y;
        ss2 += bv[i].z * bv[i].z; ss3 += bv[i].w * bv[i].w;
    }
    red[pb + 0][tc] = ss0; red[pb + 1][tc] = ss1;
    red[pb + 2][tc] = ss2; red[pb + 3][tc] = ss3;
    __syncthreads();
    if (tid < 16) {
        float B = 0.f;
        #pragma unroll
        for (int k = 0; k < 64; ++k) B += red[tid][k];
        sumsq_b[p0 + tid] = B;
        invb_sh[tid] = 1.0f / (sqrtf(B + EPS) + EPS);
    }
    __syncthreads();

    #pragma unroll
    for (int j = 0; j < 4; ++j) {
        int p = p0 + pb + j;
        float inv = invb_sh[pb + j];
        u32 w = pk4(fc(bv[0], j) * inv, fc(bv[1], j) * inv,
                    fc(bv[2], j) * inv, fc(bv[3], j) * inv);
        int lane2 = (p & 15) + ((cb & 3) << 4);
        *(u32*)(bF + (((size_t)(g * 4 + cp)) << 10) + lane2 * 16 + half * 8 + qd * 4) = w;
    }

    // ---- a: raw fragments + sumsq partials
    float4 av[4];
    ss0 = ss1 = ss2 = ss3 = 0.f;
    #pragma unroll
    for (int i = 0; i < 4; ++i) {
        av[i] = *(const float4*)&a[(size_t)(tc * 4 + i) * HW + p0 + pb];
        ss0 += av[i].x * av[i].x; ss1 += av[i].y * av[i].y;
        ss2 += av[i].z * av[i].z; ss3 += av[i].w * av[i].w;
    }
    #pragma unroll
    for (int j = 0; j < 4; ++j) {
        int p = p0 + pb + j;
        u32 w = pk4(fc(av[0], j), fc(av[1], j), fc(av[2], j), fc(av[3], j));
        int lane2 = (p & 15) + ((cb & 3) << 4);
        *(u32*)(aF + (((size_t)(g * 4 + cp)) << 10) + lane2 * 16 + half * 8 + qd * 4) = w;
    }
    __syncthreads();   // red reuse
    red[pb + 0][tc] = ss0; red[pb + 1][tc] = ss1;
    red[pb + 2][tc] = ss2; red[pb + 3][tc] = ss3;
    __syncthreads();
    if (tid < 16) {
        float A = 0.f;
        #pragma unroll
        for (int k = 0; k < 64; ++k) A += red[tid][k];
        sumsq_a[p0 + tid] = A;
    }
}

// ---------------------------------------------------------------------------
// G: fused GEMM + argmax. Register-resident A; N-loop over 16 q-substeps of
// 64 cols (NG=1024). Wave tile 64x32 (2m x 2n), 3 waves/SIMD. NEW (R13):
// 4-buffer B pipeline, prefetch distance 3 (~220cyc MFMA cover >= L2 latency
// — R12's distance-1 left MfmaUtil at 60%). At 64x32 the buffers are only
// Bfr[4][2]=32 VGPRs (R9's failure was Bfr[4][4]=64 at the 64x64 tile).
// Step s=qt*4+cp: compute from buffer cp, prefetch s+3 into (cp+3)&3 — all
// compile-time. Biased-key argmax (R12): acc init +64.0, 5-bit code in low
// mantissa bits, v_max_u32 running best; decode+shuffle-reduce+1 atomic/row.
__global__ __launch_bounds__(256, 3) void gemm_argmax(const u8* __restrict__ aF,
                                                      const u8* __restrict__ bF,
                                                      u64* __restrict__ packed) {
    const int tid = threadIdx.x;
    const int w = tid >> 6, lane = tid & 63;
    const int q4 = lane >> 4, r15 = lane & 15;
    const int wm = w >> 1, wn = w & 1;

    const u32 bid = blockIdx.x;
    const u32 ng = bid & 15;         // n-group
    const u32 mt = bid >> 4;         // 0..127 M tile
    const int p0 = (int)mt * BM;

    u32 maskv;                       // 0xFFFFFFE0 in a VGPR -> v_and_or_b32 fusion
    asm("v_mov_b32 %0, 0xFFFFFFE0" : "=v"(maskv));

    // A fragments resident: frag (mi, cp) = 16B covering k-chunks 2cp,2cp+1
    const u8* gA = aF + ((size_t)(mt * 8 + wm * 4) * 4) * 1024 + (u32)lane * 16;
    llong2 Afr[4][4];
    #pragma unroll
    for (int mi = 0; mi < 4; ++mi)
        #pragma unroll
        for (int cp = 0; cp < 4; ++cp)
            Afr[mi][cp] = *(const llong2*)(gA + (u32)(mi * 4 + cp) * 1024);

    // B: col-group (ng*64 + qt*4 + wn*2 + ni), frag cp -> +cp*1024
    const u8* gB = bF + ((size_t)(ng * 64 + wn * 2)) * 4096 + (u32)lane * 16;

    u32 bestk[4][4] = {};            // biased keys are all > 0
    const u32 qbase = ng * 1024 + wn * 32 + (u32)r15;   // + qt*64 + ni*16

    const floatx4 BIAS = {64.0f, 64.0f, 64.0f, 64.0f};

    llong2 Bfr[4][2];
    #pragma unroll
    for (int s = 0; s < 3; ++s)      // preload steps 0,1,2 (qt=0, cp=s)
        #pragma unroll
        for (int ni = 0; ni < 2; ++ni)
            Bfr[s][ni] = *(const llong2*)(gB + (u32)ni * 4096u + (u32)s * 1024u);

    for (int qt = 0; qt < 16; ++qt) {
        floatx4 acc[4][2];
        #pragma unroll
        for (int mi = 0; mi < 4; ++mi)
            #pragma unroll
            for (int ni = 0; ni < 2; ++ni)
                acc[mi][ni] = BIAS;
        #pragma unroll
        for (int cp = 0; cp < 4; ++cp) {
            // prefetch step s+3 into buffer (cp+3)&3
            int s3 = qt * 4 + cp + 3; if (s3 > 63) s3 = 63;
            u32 q3 = (u32)s3 >> 2, c3 = (u32)s3 & 3;
            #pragma unroll
            for (int ni = 0; ni < 2; ++ni)
                Bfr[(cp + 3) & 3][ni] = *(const llong2*)(gB + q3 * 16384u + (u32)ni * 4096u + c3 * 1024u);
            #pragma unroll
            for (int mi = 0; mi < 4; ++mi)
                #pragma unroll
                for (int ni = 0; ni < 2; ++ni)
                    acc[mi][ni] = __builtin_amdgcn_mfma_f32_16x16x32_fp8_fp8(
                        Afr[mi][cp].x, Bfr[cp][ni].x, acc[mi][ni], 0, 0, 0);
            #pragma unroll
            for (int mi = 0; mi < 4; ++mi)
                #pragma unroll
                for (int ni = 0; ni < 2; ++ni)
                    acc[mi][ni] = __builtin_amdgcn_mfma_f32_16x16x32_fp8_fp8(
                        Afr[mi][cp].y, Bfr[cp][ni].y, acc[mi][ni], 0, 0, 0);
        }
        // running argmax: key = (bits & ~31) | code ; best = max_u32
        #pragma unroll
        for (int ni = 0; ni < 2; ++ni) {
            const u32 code = 31u - (u32)(qt * 2 + ni);   // larger code = smaller q
            #pragma unroll
            for (int mi = 0; mi < 4; ++mi)
                #pragma unroll
                for (int reg = 0; reg < 4; ++reg) {
                    u32 key = (__float_as_uint(acc[mi][ni][reg]) & maskv) | code;
                    bestk[mi][reg] = bestk[mi][reg] > key ? bestk[mi][reg] : key;
                }
        }
    }

    // final: decode code -> q, pack u64, shuffle-reduce over r15, 1 atomic/row
    #pragma unroll
    for (int mi = 0; mi < 4; ++mi)
        #pragma unroll
        for (int reg = 0; reg < 4; ++reg) {
            u32 k = bestk[mi][reg];
            u32 code = 31u - (k & 31u);
            u32 q = qbase + (code >> 1) * 64u + (code & 1u) * 16u;
            u64 pk = ((u64)(k & 0xFFFFFFE0u) << 32) | (u64)(0xFFFFFFFFu - q);
            #pragma unroll
            for (int d = 1; d < 16; d <<= 1) {
                u64 o = __shfl_xor((unsigned long long)pk, d);
                pk = o > pk ? o : pk;
            }
            if (r15 == 0)
                atomicMax(&packed[p0 + wm * 64 + mi * 16 + q4 * 4 + reg], pk);
        }
}

// ---------------------------------------------------------------------------
// L: loss from the argmax's own similarity value (no gather).
// High 32 bits of packed = float bits of (s + 64) with low 5 bits zeroed.
__global__ void loss_kernel(const u64* __restrict__ packed,
                            const float* __restrict__ sumsq_a, const float* __restrict__ sumsq_b,
                            float* __restrict__ out) {
    int p = blockIdx.x * 256 + threadIdx.x;
    u64 pk = packed[p];
    float s = __uint_as_float((u32)(pk >> 32)) - 64.0f;
    u32 q = 0xFFFFFFFFu - (u32)(pk & 0xFFFFFFFFull);
    float A = sumsq_a[p], B = sumsq_b[q];
    float dot = s * (sqrtf(B + EPS) + EPS);
    float cossim = dot / ((sqrtf(A) + EPS) * (sqrtf(B) + EPS));
    float v = (1.0f - cossim) * (1.0f / (float)HW);
    #pragma unroll
    for (int d = 1; d < 64; d <<= 1) v += __shfl_xor(v, d);
    if ((threadIdx.x & 63) == 0) atomicAdd(out, v);
}

// ---------------------------------------------------------------------------
extern "C" void kernel_launch(void* const* d_in, const int* in_sizes, int n_in,
                              void* d_out, int out_size, void* d_ws, size_t ws_size,
                              hipStream_t stream) {
    const float* a = (const float*)d_in[0];
    const float* b = (const float*)d_in[1];
    float* out = (float*)d_out;
    char* ws = (char*)d_ws;

    u8*    aF      = (u8*)ws;                                    // 4 MB
    u8*    bF      = (u8*)(ws + (size_t)4 * 1024 * 1024);        // 4 MB
    float* sumsq_a = (float*)(ws + (size_t)8 * 1024 * 1024);     // 64 KB
    float* sumsq_b = sumsq_a + HW;
    u64*   packed  = (u64*)(sumsq_b + HW);                       // 128 KB

    prep_kernel<<<dim3(HW / 16), 256, 0, stream>>>(a, b, sumsq_a, sumsq_b, aF, bF, packed, out);
    gemm_argmax<<<dim3((HW / BM) * (HW / NG)), 256, 0, stream>>>(aF, bF, packed);
    loss_kernel<<<dim3(HW / 256), 256, 0, stream>>>(packed, sumsq_a, sumsq_b, out);
}